// Round 1
// 285.451 us; speedup vs baseline: 1.1461x; 1.1461x over previous
//
#include <hip/hip_runtime.h>
#include <hip/hip_bf16.h>
#include <hip/hip_fp16.h>

// GCNDecoder: 2-layer GCN, N=100000, E=1600000, 64 -> 128 -> 64, fp32.
//
// R1: agg-before-GEMM (linearity), dst-CSR + gather agg (no fp32 atomics).
// R2-R8 scatter lesson: workgroup->XCD placement is NOT controllable; any
//   random global 4B store/atomic costs ~32-64B HBM write (8 non-coherent
//   L2s). Fix = all random placement in LDS, HBM strictly coalesced. R8
//   removed the last per-node global atomics (hist): 388 -> 337 us.
// R3/R5: f16 gather features; agg 8-edge MLP unroll; no nt on reused lines.
// R9: (a) ebuf packed int2 -> u32 (src<<9 | dst&511); (b) dinv pre-scaled
//   into f16 features; (c) agg index prefetch. 337 -> 327 us.
// R10: agg was latency-bound, not BW-bound (26% HBM, 31% VALU, 0 MFMA):
//   one node/WAVE with 8 loads in flight exposed gather latency. Now one
//   node per 8-LANE GROUP (row = 8 lanes x uint4 = 128 B): 8 independent
//   chains/wave, 32 edges (4 KB) in flight, no cross-half shuffle, and a
//   clamped-index masked tail kills the serial remainder chain.
//
// Pipeline:
//   zero_small -> bhist(196 LDS hist) -> bscan -> bin(ebuf u32)
//   -> bucket(row_start+dinv+sorted_src, all LDS-staged)
//   -> cvt(x*dinv -> xh f16) -> agg(xh -> agg_x f16)
//   -> gemm1 (r = relu(agg_x W3 + b3), f16) -> gemm2 (t = (r W4)*dinv, f16)
//   -> agg(t -> out f32, +b4)

constexpr int IN_C  = 64;
constexpr int HID_C = 128;
constexpr int OUT_C = 64;
constexpr int BSHIFT = 9;                 // bucket width = 512 dst nodes
constexpr int BW     = 1 << BSHIFT;
constexpr int TILE   = 4096;              // bin tile (16 edges/thread)
constexpr int FCAP   = 16384;             // bucket LDS region cap (64 KB)

__device__ __forceinline__ float2 up2(unsigned u) {      // unpack f16x2
    __half2 h = *reinterpret_cast<__half2*>(&u);
    return __half22float2(h);
}
__device__ __forceinline__ unsigned pk2(float a, float b) {  // pack f16x2
    __half2 h = __float22half2_rn(make_float2(a, b));
    return *reinterpret_cast<unsigned*>(&h);
}

__global__ __launch_bounds__(256) void zero_small_kernel(int* __restrict__ p, int m)
{
    int i = blockIdx.x * 256 + threadIdx.x;
    if (i < m) p[i] = 0;
}

// Per-block LDS histogram over buckets (d>>9); one nbkt-atomic flush/block.
__global__ __launch_bounds__(256) void bhist_kernel(
    const int* __restrict__ dst, int* __restrict__ bcnt, int E, int nbkt)
{
    __shared__ int h[256];
    h[threadIdx.x] = 0;
    __syncthreads();
    const int stride = gridDim.x * 256;
    for (int e = blockIdx.x * 256 + threadIdx.x; e < E; e += stride) {
        int d = __builtin_nontemporal_load(&dst[e]);
        atomicAdd(&h[d >> BSHIFT], 1);
    }
    __syncthreads();
    if (threadIdx.x < nbkt && h[threadIdx.x] != 0)
        atomicAdd(&bcnt[threadIdx.x], h[threadIdx.x]);
}

// Single-block exclusive scan of bcnt[nbkt] -> bbase[nbkt+1]; bcur=bbase.
__global__ __launch_bounds__(256) void bscan_kernel(
    const int* __restrict__ bcnt, int* __restrict__ bbase,
    int* __restrict__ bcur, int nbkt)
{
    __shared__ int s[256];
    int v = (threadIdx.x < nbkt) ? bcnt[threadIdx.x] : 0;
    s[threadIdx.x] = v;
    __syncthreads();
    for (int off = 1; off < 256; off <<= 1) {
        int t = (threadIdx.x >= off) ? s[threadIdx.x - off] : 0;
        __syncthreads();
        s[threadIdx.x] += t;
        __syncthreads();
    }
    if (threadIdx.x < nbkt) {
        int ex = s[threadIdx.x] - v;
        bbase[threadIdx.x] = ex;
        bcur[threadIdx.x]  = ex;
        if (threadIdx.x == nbkt - 1) bbase[nbkt] = s[threadIdx.x];
    }
}

// Bin edges into nbkt contiguous regions of ebuf, PACKED u32 per edge:
// w = (src << 9) | (dst & 511). Edges live in registers (16/thread);
// bucket-grouped via LDS; flush coalesced. Parallel 256-wide scan.
__global__ __launch_bounds__(256) void bin_kernel(
    const int* __restrict__ src, const int* __restrict__ dst,
    int* __restrict__ bcur, unsigned* __restrict__ ebuf, int E, int nbkt)
{
    __shared__ unsigned stageS[TILE];           // 16 KB bucket-grouped
    __shared__ unsigned char stageB[TILE];      // 4 KB bucket ids
    __shared__ int lcnt[256], lofs[256], lpos[256], gbase[256], s[256];
    const int base = blockIdx.x * TILE;
    const int cnt_mine = min(TILE, E - base);
    const int t = threadIdx.x;
    lcnt[t] = 0;
    __syncthreads();
    unsigned w[16]; int p[16];
    #pragma unroll
    for (int k = 0; k < 16; ++k) {
        int jo = t + k * 256;
        if (jo < cnt_mine) {
            int sv = __builtin_nontemporal_load(&src[base + jo]);
            int dv = __builtin_nontemporal_load(&dst[base + jo]);
            p[k] = dv >> BSHIFT;
            w[k] = ((unsigned)sv << BSHIFT) | (unsigned)(dv & (BW - 1));
            atomicAdd(&lcnt[p[k]], 1);
        } else p[k] = -1;
    }
    __syncthreads();
    int v = lcnt[t];                             // parallel exclusive scan
    s[t] = v;
    __syncthreads();
    for (int off = 1; off < 256; off <<= 1) {
        int u = (t >= off) ? s[t - off] : 0;
        __syncthreads();
        s[t] += u;
        __syncthreads();
    }
    lofs[t] = s[t] - v;
    lpos[t] = s[t] - v;
    if (t < nbkt && v != 0) gbase[t] = atomicAdd(&bcur[t], v);
    __syncthreads();
    #pragma unroll
    for (int k = 0; k < 16; ++k) {
        if (p[k] >= 0) {
            int pos = atomicAdd(&lpos[p[k]], 1);
            stageS[pos] = w[k];
            stageB[pos] = (unsigned char)p[k];
        }
    }
    __syncthreads();
    for (int j = t; j < cnt_mine; j += 256) {
        int b = stageB[j];
        ebuf[gbase[b] + (j - lofs[b])] = stageS[j];
    }
}

// One block per bucket: per-node LDS hist of the region, LDS scan (512),
// coalesced row_start+dinv emit, LDS-cursor placement, coalesced flush.
__global__ __launch_bounds__(256) void bucket_kernel(
    const unsigned* __restrict__ ebuf, const int* __restrict__ bbase,
    int* __restrict__ row_start, float* __restrict__ dinv,
    int* __restrict__ sorted_src, int n, int E, int nbkt)
{
    __shared__ int lcnt[BW];
    __shared__ int lcur[BW];
    __shared__ int s[256];
    __shared__ int lsrc[FCAP];                // 64 KB staging
    const int b   = blockIdx.x;
    const int lo  = b << BSHIFT;
    const int hi  = min(lo + BW, n);
    const int nn  = hi - lo;
    const int beg = bbase[b], end = bbase[b + 1];
    const int cnt = end - beg;
    const int t   = threadIdx.x;
    for (int i = t; i < nn; i += 256) lcnt[i] = 0;
    __syncthreads();
    for (int j = beg + t; j < end; j += 256)
        atomicAdd(&lcnt[ebuf[j] & (BW - 1)], 1);
    __syncthreads();
    int a0 = (2 * t     < nn) ? lcnt[2 * t]     : 0;
    int a1 = (2 * t + 1 < nn) ? lcnt[2 * t + 1] : 0;
    int tsum = a0 + a1;
    s[t] = tsum;
    __syncthreads();
    for (int off = 1; off < 256; off <<= 1) {
        int v = (t >= off) ? s[t - off] : 0;
        __syncthreads();
        s[t] += v;
        __syncthreads();
    }
    int texcl = s[t] - tsum;
    if (2 * t < nn) {
        lcur[2 * t] = texcl;
        row_start[lo + 2 * t] = beg + texcl;
        dinv[lo + 2 * t] = rsqrtf((float)a0 + 1.0f);
    }
    if (2 * t + 1 < nn) {
        lcur[2 * t + 1] = texcl + a0;
        row_start[lo + 2 * t + 1] = beg + texcl + a0;
        dinv[lo + 2 * t + 1] = rsqrtf((float)a1 + 1.0f);
    }
    if (t == 0 && b == nbkt - 1) row_start[n] = E;
    __syncthreads();
    if (cnt <= FCAP) {
        for (int j = beg + t; j < end; j += 256) {
            unsigned w = ebuf[j];
            int pos = atomicAdd(&lcur[w & (BW - 1)], 1);
            lsrc[pos] = (int)(w >> BSHIFT);
        }
        __syncthreads();
        for (int j = t; j < cnt; j += 256)
            sorted_src[beg + j] = lsrc[j];
    } else {                                  // safety net (never on this graph)
        for (int j = beg + t; j < end; j += 256) {
            unsigned w = ebuf[j];
            int pos = atomicAdd(&lcur[w & (BW - 1)], 1);
            sorted_src[beg + pos] = (int)(w >> BSHIFT);
        }
    }
}

// Pack 2 fp32 channels into f16x2, PRE-SCALED by dinv[row] (row = i>>5).
__global__ __launch_bounds__(256) void cvt_scaled_kernel(
    const float2* __restrict__ in, const float* __restrict__ dinv,
    unsigned* __restrict__ outw, int nw)
{
    int i = blockIdx.x * 256 + threadIdx.x;
    if (i < nw) {
        float2 v = in[i];
        float dv = dinv[i >> 5];
        outw[i] = pk2(v.x * dv, v.y * dv);
    }
}

// One dst node per 8-LANE GROUP (8 nodes/wave, 32/block). A feature row is
// 128 B = 8 lanes x uint4; lane gl owns channels 8*gl..8*gl+7 for the whole
// node -> no cross-lane reduction. 4 edge-rows in flight per group (32 per
// wave); next batch's indices prefetched while gathers are outstanding; the
// tail batch uses clamped indices (re-reads last edge's row, L1-hit) with
// group-uniform masked accumulation -> no serial remainder chain.
// feat is packed f16, PRE-SCALED by dinv[src].
// out[d] = dinv_d * (feat'[d] + sum_s feat'[s]) [+ bias].
template <bool OUT_F16, bool ADD_BIAS>
__global__ __launch_bounds__(256) void agg_f16_kernel(
    const unsigned* __restrict__ feat, const int* __restrict__ row_start,
    const int* __restrict__ sorted_src, const float* __restrict__ dinv,
    const float* __restrict__ bias, void* __restrict__ outp, int n)
{
    const int g  = threadIdx.x >> 3;    // group in block (0..31)
    const int gl = threadIdx.x & 7;     // lane in group
    const int d  = blockIdx.x * 32 + g;
    if (d >= n) return;                 // group-uniform exit (no barriers)
    const float di = dinv[d];
    const uint4* f4 = (const uint4*)feat;

    float a0x, a0y, a1x, a1y, a2x, a2y, a3x, a3y;
    {   // self-loop term (feat already scaled by dinv[d])
        uint4 u = f4[(size_t)d * 8 + gl];
        float2 f0 = up2(u.x), f1 = up2(u.y), f2 = up2(u.z), f3 = up2(u.w);
        a0x = f0.x; a0y = f0.y; a1x = f1.x; a1y = f1.y;
        a2x = f2.x; a2y = f2.y; a3x = f3.x; a3y = f3.y;
    }

#define ACC(U) do { \
        float2 f0_ = up2((U).x), f1_ = up2((U).y), f2_ = up2((U).z), f3_ = up2((U).w); \
        a0x += f0_.x; a0y += f0_.y; a1x += f1_.x; a1y += f1_.y; \
        a2x += f2_.x; a2y += f2_.y; a3x += f3_.x; a3y += f3_.y; } while (0)

    const int beg = row_start[d], end = row_start[d + 1];
    const int last = end - 1;
    int i = beg;
    int s0, s1, s2, s3;
    if (i < end) {                      // prologue: first (clamped) batch
        s0 = sorted_src[i];
        s1 = sorted_src[min(i + 1, last)];
        s2 = sorted_src[min(i + 2, last)];
        s3 = sorted_src[min(i + 3, last)];
    }
    while (i < end) {
        uint4 u0 = f4[(size_t)s0 * 8 + gl];
        uint4 u1 = f4[(size_t)s1 * 8 + gl];
        uint4 u2 = f4[(size_t)s2 * 8 + gl];
        uint4 u3 = f4[(size_t)s3 * 8 + gl];
        const int ni = i + 4;
        if (ni < end) {                 // prefetch next batch's indices
            s0 = sorted_src[ni];
            s1 = sorted_src[min(ni + 1, last)];
            s2 = sorted_src[min(ni + 2, last)];
            s3 = sorted_src[min(ni + 3, last)];
        }
        const int nb = end - i;         // valid edges in this batch
        ACC(u0);
        if (nb > 1) ACC(u1);
        if (nb > 2) ACC(u2);
        if (nb > 3) ACC(u3);
        i = ni;
    }
#undef ACC

    a0x *= di; a0y *= di; a1x *= di; a1y *= di;
    a2x *= di; a2y *= di; a3x *= di; a3y *= di;
    if (ADD_BIAS) {
        const float4 b0 = ((const float4*)bias)[gl * 2];
        const float4 b1 = ((const float4*)bias)[gl * 2 + 1];
        a0x += b0.x; a0y += b0.y; a1x += b0.z; a1y += b0.w;
        a2x += b1.x; a2y += b1.y; a3x += b1.z; a3y += b1.w;
    }
    if (OUT_F16) {
        uint4 o;
        o.x = pk2(a0x, a0y); o.y = pk2(a1x, a1y);
        o.z = pk2(a2x, a2y); o.w = pk2(a3x, a3y);
        ((uint4*)outp)[(size_t)d * 8 + gl] = o;
    } else {
        float4* op = (float4*)outp;
        op[(size_t)d * 16 + gl * 2]     = make_float4(a0x, a0y, a1x, a1y);
        op[(size_t)d * 16 + gl * 2 + 1] = make_float4(a2x, a2y, a3x, a3y);
    }
}

// r[row][c] = relu(sum_k agg_x[row][k] * W3[k][c] + b3[c]), r stored f16x2.
__global__ __launch_bounds__(256) void gemm1_kernel(
    const unsigned* __restrict__ xh, const float* __restrict__ W,
    const float* __restrict__ b, unsigned* __restrict__ rout, int n)
{
    __shared__ float Ws[IN_C * HID_C];   // 32 KB
    __shared__ float xs[64][IN_C + 1];   // 16.6 KB
    for (int i = threadIdx.x; i < IN_C * HID_C; i += 256) Ws[i] = W[i];
    const int r0 = blockIdx.x * 64;
    for (int i = threadIdx.x; i < 64 * 32; i += 256) {
        int row = i >> 5, c = i & 31;
        int r = r0 + row;
        float2 f = up2((r < n) ? xh[(size_t)r * 32 + c] : 0u);
        xs[row][c * 2]     = f.x;
        xs[row][c * 2 + 1] = f.y;
    }
    __syncthreads();
    const int ct = threadIdx.x & 15;   // 16 x 8 = 128 cols
    const int rt = threadIdx.x >> 4;   // 16 x 4 = 64 rows
    float acc[4][8] = {};
    const float4* Ws4 = (const float4*)Ws;
    for (int k = 0; k < IN_C; ++k) {
        float4 w0 = Ws4[k * 32 + ct * 2];
        float4 w1 = Ws4[k * 32 + ct * 2 + 1];
        #pragma unroll
        for (int ry = 0; ry < 4; ++ry) {
            float xv = xs[rt * 4 + ry][k];
            acc[ry][0] += xv * w0.x; acc[ry][1] += xv * w0.y;
            acc[ry][2] += xv * w0.z; acc[ry][3] += xv * w0.w;
            acc[ry][4] += xv * w1.x; acc[ry][5] += xv * w1.y;
            acc[ry][6] += xv * w1.z; acc[ry][7] += xv * w1.w;
        }
    }
    float4 b0 = ((const float4*)b)[ct * 2];
    float4 b1 = ((const float4*)b)[ct * 2 + 1];
    #pragma unroll
    for (int ry = 0; ry < 4; ++ry) {
        int r = r0 + rt * 4 + ry;
        if (r < n) {
            uint4 o;
            o.x = pk2(fmaxf(acc[ry][0] + b0.x, 0.0f), fmaxf(acc[ry][1] + b0.y, 0.0f));
            o.y = pk2(fmaxf(acc[ry][2] + b0.z, 0.0f), fmaxf(acc[ry][3] + b0.w, 0.0f));
            o.z = pk2(fmaxf(acc[ry][4] + b1.x, 0.0f), fmaxf(acc[ry][5] + b1.y, 0.0f));
            o.w = pk2(fmaxf(acc[ry][6] + b1.z, 0.0f), fmaxf(acc[ry][7] + b1.w, 0.0f));
            *(uint4*)&rout[(size_t)r * 64 + ct * 4] = o;
        }
    }
}

// t[row][c] = dinv[row] * sum_k r[row][k] * W4[k][c], stored f16x2.
__global__ __launch_bounds__(256) void gemm2_kernel(
    const unsigned* __restrict__ rin, const float* __restrict__ W,
    const float* __restrict__ dinv, unsigned* __restrict__ tout, int n)
{
    __shared__ unsigned Wh[HID_C * 32];  // 16 KB
    __shared__ float xs[64][HID_C + 1];  // 33 KB
    for (int i = threadIdx.x; i < HID_C * 32; i += 256) {
        int k = i >> 5, cp = i & 31;
        Wh[i] = pk2(W[k * OUT_C + cp * 2], W[k * OUT_C + cp * 2 + 1]);
    }
    const int r0 = blockIdx.x * 64;
    for (int i = threadIdx.x; i < 64 * 64; i += 256) {
        int row = i >> 6, c = i & 63;
        int r = r0 + row;
        float2 f = up2((r < n) ? rin[(size_t)r * 64 + c] : 0u);
        xs[row][c * 2]     = f.x;
        xs[row][c * 2 + 1] = f.y;
    }
    __syncthreads();
    const int ct = threadIdx.x & 7;    // 8 x 8 = 64 cols
    const int rt = threadIdx.x >> 3;   // 32 x 2 = 64 rows
    float acc[2][8] = {};
    for (int k = 0; k < HID_C; ++k) {
        uint4 wq = *(const uint4*)&Wh[k * 32 + ct * 4];
        float2 wa = up2(wq.x), wb = up2(wq.y), wc = up2(wq.z), wd = up2(wq.w);
        #pragma unroll
        for (int ry = 0; ry < 2; ++ry) {
            float xv = xs[rt * 2 + ry][k];
            acc[ry][0] += xv * wa.x; acc[ry][1] += xv * wa.y;
            acc[ry][2] += xv * wb.x; acc[ry][3] += xv * wb.y;
            acc[ry][4] += xv * wc.x; acc[ry][5] += xv * wc.y;
            acc[ry][6] += xv * wd.x; acc[ry][7] += xv * wd.y;
        }
    }
    #pragma unroll
    for (int ry = 0; ry < 2; ++ry) {
        int r = r0 + rt * 2 + ry;
        if (r < n) {
            float dv = dinv[r];
            uint4 o;
            o.x = pk2(acc[ry][0] * dv, acc[ry][1] * dv);
            o.y = pk2(acc[ry][2] * dv, acc[ry][3] * dv);
            o.z = pk2(acc[ry][4] * dv, acc[ry][5] * dv);
            o.w = pk2(acc[ry][6] * dv, acc[ry][7] * dv);
            *(uint4*)&tout[(size_t)r * 32 + ct * 4] = o;
        }
    }
}

extern "C" void kernel_launch(void* const* d_in, const int* in_sizes, int n_in,
                              void* d_out, int out_size, void* d_ws, size_t ws_size,
                              hipStream_t stream)
{
    const float* x  = (const float*)d_in[0];
    const int*   ei = (const int*)d_in[1];
    const float* W3 = (const float*)d_in[2];
    const float* b3 = (const float*)d_in[3];
    const float* W4 = (const float*)d_in[4];
    const float* b4 = (const float*)d_in[5];
    float* out = (float*)d_out;

    const int n = in_sizes[0] / IN_C;   // 100000
    const int E = in_sizes[1] / 2;      // 1600000
    const int* src = ei;
    const int* dst = ei + E;
    const int nbkt = (n + BW - 1) >> BSHIFT;   // 196

    const size_t n_pad = ((size_t)n + 256) & ~(size_t)255;  // room for row_start[n]

    // Workspace: bcnt(256) | bbase(512) | bcur(256) | row_start | dinv |
    //            ssrc | ebuf (E u32) | xh (n*32 u32, reused as t) |
    //            agg_x (n*32 u32) | r (n*64 u32)
    int*      bcnt      = (int*)d_ws;
    int*      bbase     = bcnt + 256;
    int*      bcur      = bbase + 512;
    int*      row_start = bcur + 256;
    float*    dinv      = (float*)(row_start + n_pad);
    int*      ssrc      = (int*)(dinv + n_pad);
    unsigned* ebuf      = (unsigned*)(ssrc + (((size_t)E + 255) & ~(size_t)255));
    unsigned* xh        = ebuf + (((size_t)E + 255) & ~(size_t)255);
    unsigned* agg_x     = xh + n_pad * 32;
    unsigned* r         = agg_x + n_pad * 32;
    unsigned* t         = xh;                      // xh dead after agg1

    zero_small_kernel<<<1, 256, 0, stream>>>(bcnt, 256);
    bhist_kernel<<<256, 256, 0, stream>>>(dst, bcnt, E, nbkt);
    bscan_kernel<<<1, 256, 0, stream>>>(bcnt, bbase, bcur, nbkt);

    bin_kernel<<<(E + TILE - 1) / TILE, 256, 0, stream>>>(src, dst, bcur, ebuf, E, nbkt);
    bucket_kernel<<<nbkt, 256, 0, stream>>>(ebuf, bbase, row_start, dinv, ssrc, n, E, nbkt);

    cvt_scaled_kernel<<<(n * 32 + 255) / 256, 256, 0, stream>>>(
        (const float2*)x, dinv, xh, n * 32);

    agg_f16_kernel<true, false><<<(n + 31) / 32, 256, 0, stream>>>(
        xh, row_start, ssrc, dinv, nullptr, agg_x, n);

    gemm1_kernel<<<(n + 63) / 64, 256, 0, stream>>>(agg_x, W3, b3, r, n);
    gemm2_kernel<<<(n + 63) / 64, 256, 0, stream>>>(r, W4, dinv, t, n);

    agg_f16_kernel<false, true><<<(n + 31) / 32, 256, 0, stream>>>(
        t, row_start, ssrc, dinv, b4, out, n);
}

// Round 2
// 228.368 us; speedup vs baseline: 1.4326x; 1.2500x over previous
//
#include <hip/hip_runtime.h>
#include <hip/hip_bf16.h>
#include <hip/hip_fp16.h>

// GCNDecoder: 2-layer GCN, N=100000, E=1600000, 64 -> 128 -> 64, fp32.
//
// R1: agg-before-GEMM (linearity), dst-CSR + gather agg (no fp32 atomics).
// R2-R8 scatter lesson: workgroup->XCD placement is NOT controllable; any
//   random global 4B store/atomic costs ~32-64B HBM write (8 non-coherent
//   L2s). Fix = all random placement in LDS, HBM strictly coalesced.
// R3/R5: f16 gather features; R9: ebuf packed u32; dinv pre-scaled feats.
// R10: agg latency-bound -> one node per 8-LANE GROUP (row = 8 x uint4),
//   8 chains/wave, 32 edges in flight, clamped masked tail. 327 -> 285 us.
// R11: gemm1+gemm2 were VALU GEMMs (MfmaUtil=0, VALUBusy 42%, occ 24%,
//   ~100 us combined). Replaced by ONE fused MFMA kernel (16x16x32_f16):
//   per 32-row wave: stage1 relu(agg_x W3 + b3) -> wave-private swizzled
//   LDS tile (r never hits HBM), stage2 (r W4)*dinv -> t. Weights pre-
//   packed into per-lane B-fragments (wfrag); W3 split hi/lo f16 to keep
//   stage-1 at effective-f32 weight precision.
//
// Pipeline:
//   zero_small -> wfrag -> bhist -> bscan -> bin(ebuf u32)
//   -> bucket(row_start+dinv+sorted_src) -> cvt(x*dinv -> xh f16)
//   -> agg(xh -> agg_x f16) -> gemm12 (t = (relu(agg_x W3+b3) W4)*dinv)
//   -> agg(t -> out f32, +b4)

constexpr int IN_C  = 64;
constexpr int HID_C = 128;
constexpr int OUT_C = 64;
constexpr int BSHIFT = 9;                 // bucket width = 512 dst nodes
constexpr int BW     = 1 << BSHIFT;
constexpr int TILE   = 4096;              // bin tile (16 edges/thread)
constexpr int FCAP   = 16384;             // bucket LDS region cap (64 KB)

typedef _Float16 f16x8 __attribute__((ext_vector_type(8)));
typedef float    f32x4 __attribute__((ext_vector_type(4)));

union FragU { uint4 u; f16x8 h; _Float16 q[8]; };

__device__ __forceinline__ f32x4 mfma16(f16x8 a, f16x8 b, f32x4 c) {
    return __builtin_amdgcn_mfma_f32_16x16x32_f16(a, b, c, 0, 0, 0);
}

__device__ __forceinline__ float2 up2(unsigned u) {      // unpack f16x2
    __half2 h = *reinterpret_cast<__half2*>(&u);
    return __half22float2(h);
}
__device__ __forceinline__ unsigned pk2(float a, float b) {  // pack f16x2
    __half2 h = __float22half2_rn(make_float2(a, b));
    return *reinterpret_cast<unsigned*>(&h);
}

__global__ __launch_bounds__(256) void zero_small_kernel(int* __restrict__ p, int m)
{
    int i = blockIdx.x * 256 + threadIdx.x;
    if (i < m) p[i] = 0;
}

// Pre-pack weights into per-lane MFMA B-fragments (8 contiguous K elems per
// lane; lanes&15 = col, lanes>>4 = K-chunk).  W3: hi/lo f16 split (fi =
// c*4 + s*2 + h, 32 frags).  W4: single f16 (fi = c*4 + s, 16 frags).
__global__ __launch_bounds__(256) void wfrag_kernel(
    const float* __restrict__ W3, const float* __restrict__ W4,
    uint4* __restrict__ w3f, uint4* __restrict__ w4f)
{
    const int idx = blockIdx.x * 256 + threadIdx.x;
    const int l = idx & 63, cl = l & 15, ch = l >> 4;
    if (idx < 2048) {                       // W3: 32 frags x 64 lanes
        const int fi = idx >> 6;
        const int h = fi & 1, s = (fi >> 1) & 1, c = fi >> 2;
        const int k0 = s * 32 + ch * 8, col = c * 16 + cl;
        FragU f;
        #pragma unroll
        for (int i = 0; i < 8; ++i) {
            float x = W3[(k0 + i) * HID_C + col];
            _Float16 hi = (_Float16)x;
            f.q[i] = h ? (_Float16)(x - (float)hi) : hi;
        }
        w3f[fi * 64 + l] = f.u;
    } else if (idx < 3072) {                // W4: 16 frags x 64 lanes
        const int fi = (idx - 2048) >> 6;
        const int s = fi & 3, c = fi >> 2;
        const int k0 = s * 32 + ch * 8, col = c * 16 + cl;
        FragU f;
        #pragma unroll
        for (int i = 0; i < 8; ++i)
            f.q[i] = (_Float16)W4[(k0 + i) * OUT_C + col];
        w4f[fi * 64 + l] = f.u;
    }
}

// Per-block LDS histogram over buckets (d>>9); one nbkt-atomic flush/block.
__global__ __launch_bounds__(256) void bhist_kernel(
    const int* __restrict__ dst, int* __restrict__ bcnt, int E, int nbkt)
{
    __shared__ int h[256];
    h[threadIdx.x] = 0;
    __syncthreads();
    const int stride = gridDim.x * 256;
    for (int e = blockIdx.x * 256 + threadIdx.x; e < E; e += stride) {
        int d = __builtin_nontemporal_load(&dst[e]);
        atomicAdd(&h[d >> BSHIFT], 1);
    }
    __syncthreads();
    if (threadIdx.x < nbkt && h[threadIdx.x] != 0)
        atomicAdd(&bcnt[threadIdx.x], h[threadIdx.x]);
}

// Single-block exclusive scan of bcnt[nbkt] -> bbase[nbkt+1]; bcur=bbase.
__global__ __launch_bounds__(256) void bscan_kernel(
    const int* __restrict__ bcnt, int* __restrict__ bbase,
    int* __restrict__ bcur, int nbkt)
{
    __shared__ int s[256];
    int v = (threadIdx.x < nbkt) ? bcnt[threadIdx.x] : 0;
    s[threadIdx.x] = v;
    __syncthreads();
    for (int off = 1; off < 256; off <<= 1) {
        int t = (threadIdx.x >= off) ? s[threadIdx.x - off] : 0;
        __syncthreads();
        s[threadIdx.x] += t;
        __syncthreads();
    }
    if (threadIdx.x < nbkt) {
        int ex = s[threadIdx.x] - v;
        bbase[threadIdx.x] = ex;
        bcur[threadIdx.x]  = ex;
        if (threadIdx.x == nbkt - 1) bbase[nbkt] = s[threadIdx.x];
    }
}

// Bin edges into nbkt contiguous regions of ebuf, PACKED u32 per edge:
// w = (src << 9) | (dst & 511). Edges live in registers (16/thread);
// bucket-grouped via LDS; flush coalesced. Parallel 256-wide scan.
__global__ __launch_bounds__(256) void bin_kernel(
    const int* __restrict__ src, const int* __restrict__ dst,
    int* __restrict__ bcur, unsigned* __restrict__ ebuf, int E, int nbkt)
{
    __shared__ unsigned stageS[TILE];           // 16 KB bucket-grouped
    __shared__ unsigned char stageB[TILE];      // 4 KB bucket ids
    __shared__ int lcnt[256], lofs[256], lpos[256], gbase[256], s[256];
    const int base = blockIdx.x * TILE;
    const int cnt_mine = min(TILE, E - base);
    const int t = threadIdx.x;
    lcnt[t] = 0;
    __syncthreads();
    unsigned w[16]; int p[16];
    #pragma unroll
    for (int k = 0; k < 16; ++k) {
        int jo = t + k * 256;
        if (jo < cnt_mine) {
            int sv = __builtin_nontemporal_load(&src[base + jo]);
            int dv = __builtin_nontemporal_load(&dst[base + jo]);
            p[k] = dv >> BSHIFT;
            w[k] = ((unsigned)sv << BSHIFT) | (unsigned)(dv & (BW - 1));
            atomicAdd(&lcnt[p[k]], 1);
        } else p[k] = -1;
    }
    __syncthreads();
    int v = lcnt[t];                             // parallel exclusive scan
    s[t] = v;
    __syncthreads();
    for (int off = 1; off < 256; off <<= 1) {
        int u = (t >= off) ? s[t - off] : 0;
        __syncthreads();
        s[t] += u;
        __syncthreads();
    }
    lofs[t] = s[t] - v;
    lpos[t] = s[t] - v;
    if (t < nbkt && v != 0) gbase[t] = atomicAdd(&bcur[t], v);
    __syncthreads();
    #pragma unroll
    for (int k = 0; k < 16; ++k) {
        if (p[k] >= 0) {
            int pos = atomicAdd(&lpos[p[k]], 1);
            stageS[pos] = w[k];
            stageB[pos] = (unsigned char)p[k];
        }
    }
    __syncthreads();
    for (int j = t; j < cnt_mine; j += 256) {
        int b = stageB[j];
        ebuf[gbase[b] + (j - lofs[b])] = stageS[j];
    }
}

// One block per bucket: per-node LDS hist of the region, LDS scan (512),
// coalesced row_start+dinv emit, LDS-cursor placement, coalesced flush.
__global__ __launch_bounds__(256) void bucket_kernel(
    const unsigned* __restrict__ ebuf, const int* __restrict__ bbase,
    int* __restrict__ row_start, float* __restrict__ dinv,
    int* __restrict__ sorted_src, int n, int E, int nbkt)
{
    __shared__ int lcnt[BW];
    __shared__ int lcur[BW];
    __shared__ int s[256];
    __shared__ int lsrc[FCAP];                // 64 KB staging
    const int b   = blockIdx.x;
    const int lo  = b << BSHIFT;
    const int hi  = min(lo + BW, n);
    const int nn  = hi - lo;
    const int beg = bbase[b], end = bbase[b + 1];
    const int cnt = end - beg;
    const int t   = threadIdx.x;
    for (int i = t; i < nn; i += 256) lcnt[i] = 0;
    __syncthreads();
    for (int j = beg + t; j < end; j += 256)
        atomicAdd(&lcnt[ebuf[j] & (BW - 1)], 1);
    __syncthreads();
    int a0 = (2 * t     < nn) ? lcnt[2 * t]     : 0;
    int a1 = (2 * t + 1 < nn) ? lcnt[2 * t + 1] : 0;
    int tsum = a0 + a1;
    s[t] = tsum;
    __syncthreads();
    for (int off = 1; off < 256; off <<= 1) {
        int v = (t >= off) ? s[t - off] : 0;
        __syncthreads();
        s[t] += v;
        __syncthreads();
    }
    int texcl = s[t] - tsum;
    if (2 * t < nn) {
        lcur[2 * t] = texcl;
        row_start[lo + 2 * t] = beg + texcl;
        dinv[lo + 2 * t] = rsqrtf((float)a0 + 1.0f);
    }
    if (2 * t + 1 < nn) {
        lcur[2 * t + 1] = texcl + a0;
        row_start[lo + 2 * t + 1] = beg + texcl + a0;
        dinv[lo + 2 * t + 1] = rsqrtf((float)a1 + 1.0f);
    }
    if (t == 0 && b == nbkt - 1) row_start[n] = E;
    __syncthreads();
    if (cnt <= FCAP) {
        for (int j = beg + t; j < end; j += 256) {
            unsigned w = ebuf[j];
            int pos = atomicAdd(&lcur[w & (BW - 1)], 1);
            lsrc[pos] = (int)(w >> BSHIFT);
        }
        __syncthreads();
        for (int j = t; j < cnt; j += 256)
            sorted_src[beg + j] = lsrc[j];
    } else {                                  // safety net (never on this graph)
        for (int j = beg + t; j < end; j += 256) {
            unsigned w = ebuf[j];
            int pos = atomicAdd(&lcur[w & (BW - 1)], 1);
            sorted_src[beg + pos] = (int)(w >> BSHIFT);
        }
    }
}

// Pack 2 fp32 channels into f16x2, PRE-SCALED by dinv[row] (row = i>>5).
__global__ __launch_bounds__(256) void cvt_scaled_kernel(
    const float2* __restrict__ in, const float* __restrict__ dinv,
    unsigned* __restrict__ outw, int nw)
{
    int i = blockIdx.x * 256 + threadIdx.x;
    if (i < nw) {
        float2 v = in[i];
        float dv = dinv[i >> 5];
        outw[i] = pk2(v.x * dv, v.y * dv);
    }
}

// One dst node per 8-LANE GROUP (8 nodes/wave, 32/block). A feature row is
// 128 B = 8 lanes x uint4; lane gl owns channels 8*gl..8*gl+7 for the whole
// node -> no cross-lane reduction. 4 edge-rows in flight per group (32 per
// wave); next batch's indices prefetched while gathers are outstanding; the
// tail batch uses clamped indices with group-uniform masked accumulation.
// feat is packed f16, PRE-SCALED by dinv[src].
// out[d] = dinv_d * (feat'[d] + sum_s feat'[s]) [+ bias].
template <bool OUT_F16, bool ADD_BIAS>
__global__ __launch_bounds__(256) void agg_f16_kernel(
    const unsigned* __restrict__ feat, const int* __restrict__ row_start,
    const int* __restrict__ sorted_src, const float* __restrict__ dinv,
    const float* __restrict__ bias, void* __restrict__ outp, int n)
{
    const int g  = threadIdx.x >> 3;    // group in block (0..31)
    const int gl = threadIdx.x & 7;     // lane in group
    const int d  = blockIdx.x * 32 + g;
    if (d >= n) return;                 // group-uniform exit (no barriers)
    const float di = dinv[d];
    const uint4* f4 = (const uint4*)feat;

    float a0x, a0y, a1x, a1y, a2x, a2y, a3x, a3y;
    {   // self-loop term (feat already scaled by dinv[d])
        uint4 u = f4[(size_t)d * 8 + gl];
        float2 f0 = up2(u.x), f1 = up2(u.y), f2 = up2(u.z), f3 = up2(u.w);
        a0x = f0.x; a0y = f0.y; a1x = f1.x; a1y = f1.y;
        a2x = f2.x; a2y = f2.y; a3x = f3.x; a3y = f3.y;
    }

#define ACC(U) do { \
        float2 f0_ = up2((U).x), f1_ = up2((U).y), f2_ = up2((U).z), f3_ = up2((U).w); \
        a0x += f0_.x; a0y += f0_.y; a1x += f1_.x; a1y += f1_.y; \
        a2x += f2_.x; a2y += f2_.y; a3x += f3_.x; a3y += f3_.y; } while (0)

    const int beg = row_start[d], end = row_start[d + 1];
    const int last = end - 1;
    int i = beg;
    int s0, s1, s2, s3;
    if (i < end) {                      // prologue: first (clamped) batch
        s0 = sorted_src[i];
        s1 = sorted_src[min(i + 1, last)];
        s2 = sorted_src[min(i + 2, last)];
        s3 = sorted_src[min(i + 3, last)];
    }
    while (i < end) {
        uint4 u0 = f4[(size_t)s0 * 8 + gl];
        uint4 u1 = f4[(size_t)s1 * 8 + gl];
        uint4 u2 = f4[(size_t)s2 * 8 + gl];
        uint4 u3 = f4[(size_t)s3 * 8 + gl];
        const int ni = i + 4;
        if (ni < end) {                 // prefetch next batch's indices
            s0 = sorted_src[ni];
            s1 = sorted_src[min(ni + 1, last)];
            s2 = sorted_src[min(ni + 2, last)];
            s3 = sorted_src[min(ni + 3, last)];
        }
        const int nb = end - i;         // valid edges in this batch
        ACC(u0);
        if (nb > 1) ACC(u1);
        if (nb > 2) ACC(u2);
        if (nb > 3) ACC(u3);
        i = ni;
    }
#undef ACC

    a0x *= di; a0y *= di; a1x *= di; a1y *= di;
    a2x *= di; a2y *= di; a3x *= di; a3y *= di;
    if (ADD_BIAS) {
        const float4 b0 = ((const float4*)bias)[gl * 2];
        const float4 b1 = ((const float4*)bias)[gl * 2 + 1];
        a0x += b0.x; a0y += b0.y; a1x += b0.z; a1y += b0.w;
        a2x += b1.x; a2y += b1.y; a3x += b1.z; a3y += b1.w;
    }
    if (OUT_F16) {
        uint4 o;
        o.x = pk2(a0x, a0y); o.y = pk2(a1x, a1y);
        o.z = pk2(a2x, a2y); o.w = pk2(a3x, a3y);
        ((uint4*)outp)[(size_t)d * 8 + gl] = o;
    } else {
        float4* op = (float4*)outp;
        op[(size_t)d * 16 + gl * 2]     = make_float4(a0x, a0y, a1x, a1y);
        op[(size_t)d * 16 + gl * 2 + 1] = make_float4(a2x, a2y, a3x, a3y);
    }
}

// Fused MFMA GEMM: t = (relu(agg_x W3 + b3) W4) * dinv, all f16 activations.
// 4 waves/block, 32 rows/wave (2 row-tiles of 16). Stage-1 output lives in
// a WAVE-PRIVATE XOR-swizzled LDS tile (same-wave dep -> no barrier).
// MFMA frag convention (m89/m92-verified): A lane: row=l&15, k=(l>>4)*8+i
// (8 contiguous K halves = one uint4); B lane: col=l&15, same K chunks;
// D lane: col=l&15, row=(l>>4)*4+reg.
__global__ __launch_bounds__(256) void gemm12_kernel(
    const unsigned* __restrict__ ax, const uint4* __restrict__ w3f,
    const uint4* __restrict__ w4f, const float* __restrict__ b3,
    const float* __restrict__ dinv, unsigned* __restrict__ t, int n)
{
    __shared__ __align__(16) char lds[32768];   // 4 waves x 2 tiles x 4 KB
    const int l  = threadIdx.x & 63;
    const int wv = threadIdx.x >> 6;
    const int cl = l & 15, ch = l >> 4;
    const int r0 = blockIdx.x * 128 + wv * 32;

    // ---- stage 1: r = relu(agg_x W3 + b3) -> LDS (f16) ----
    FragU a1[2][2];
    const uint4* ax4 = (const uint4*)ax;        // 8 uint4 per row
    #pragma unroll
    for (int rt = 0; rt < 2; ++rt)
        #pragma unroll
        for (int s = 0; s < 2; ++s)
            a1[rt][s].u = ax4[(size_t)(r0 + rt * 16 + cl) * 8 + s * 4 + ch];

    float bb[8];
    #pragma unroll
    for (int c = 0; c < 8; ++c) bb[c] = b3[c * 16 + cl];

    const f32x4 z4 = {0.f, 0.f, 0.f, 0.f};
    f32x4 acc1[2][8];
    #pragma unroll
    for (int rt = 0; rt < 2; ++rt)
        #pragma unroll
        for (int c = 0; c < 8; ++c) acc1[rt][c] = z4;

    #pragma unroll
    for (int c = 0; c < 8; ++c) {
        FragU bh0, bl0, bh1, bl1;               // W3 hi/lo split per k-step
        bh0.u = w3f[(c * 4 + 0) * 64 + l];
        bl0.u = w3f[(c * 4 + 1) * 64 + l];
        bh1.u = w3f[(c * 4 + 2) * 64 + l];
        bl1.u = w3f[(c * 4 + 3) * 64 + l];
        #pragma unroll
        for (int rt = 0; rt < 2; ++rt) {
            f32x4 a = acc1[rt][c];
            a = mfma16(a1[rt][0].h, bh0.h, a);
            a = mfma16(a1[rt][0].h, bl0.h, a);
            a = mfma16(a1[rt][1].h, bh1.h, a);
            a = mfma16(a1[rt][1].h, bl1.h, a);
            acc1[rt][c] = a;
        }
    }

    #pragma unroll
    for (int rt = 0; rt < 2; ++rt) {
        const int tb = (wv * 2 + rt) * 4096;
        #pragma unroll
        for (int c = 0; c < 8; ++c)
            #pragma unroll
            for (int i = 0; i < 4; ++i) {
                int row = ch * 4 + i;
                int off = tb + ((row * 256 + (c * 16 + cl) * 2) ^ ((row & 7) << 4));
                *(_Float16*)&lds[off] =
                    (_Float16)fmaxf(acc1[rt][c][i] + bb[c], 0.0f);
            }
    }

    // ---- stage 2: t = (r W4) * dinv ----
    float dv[2][4];
    #pragma unroll
    for (int rt = 0; rt < 2; ++rt)
        #pragma unroll
        for (int i = 0; i < 4; ++i)
            dv[rt][i] = dinv[min(r0 + rt * 16 + ch * 4 + i, n - 1)];

    FragU a2[2][4];
    #pragma unroll
    for (int rt = 0; rt < 2; ++rt) {
        const int tb = (wv * 2 + rt) * 4096;
        #pragma unroll
        for (int s2 = 0; s2 < 4; ++s2) {
            int off = tb + ((cl * 256 + s2 * 64 + ch * 16) ^ ((cl & 7) << 4));
            a2[rt][s2].u = *(const uint4*)&lds[off];
        }
    }

    f32x4 acc2[2][4];
    #pragma unroll
    for (int rt = 0; rt < 2; ++rt)
        #pragma unroll
        for (int c2 = 0; c2 < 4; ++c2) acc2[rt][c2] = z4;

    #pragma unroll
    for (int c2 = 0; c2 < 4; ++c2)
        #pragma unroll
        for (int s2 = 0; s2 < 4; ++s2) {
            FragU b2; b2.u = w4f[(c2 * 4 + s2) * 64 + l];
            acc2[0][c2] = mfma16(a2[0][s2].h, b2.h, acc2[0][c2]);
            acc2[1][c2] = mfma16(a2[1][s2].h, b2.h, acc2[1][c2]);
        }

    _Float16* th = (_Float16*)t;
    #pragma unroll
    for (int rt = 0; rt < 2; ++rt)
        #pragma unroll
        for (int i = 0; i < 4; ++i) {
            int row = r0 + rt * 16 + ch * 4 + i;
            if (row < n) {
                #pragma unroll
                for (int c2 = 0; c2 < 4; ++c2)
                    th[(size_t)row * 64 + c2 * 16 + cl] =
                        (_Float16)(acc2[rt][c2][i] * dv[rt][i]);
            }
        }
}

extern "C" void kernel_launch(void* const* d_in, const int* in_sizes, int n_in,
                              void* d_out, int out_size, void* d_ws, size_t ws_size,
                              hipStream_t stream)
{
    const float* x  = (const float*)d_in[0];
    const int*   ei = (const int*)d_in[1];
    const float* W3 = (const float*)d_in[2];
    const float* b3 = (const float*)d_in[3];
    const float* W4 = (const float*)d_in[4];
    const float* b4 = (const float*)d_in[5];
    float* out = (float*)d_out;

    const int n = in_sizes[0] / IN_C;   // 100000
    const int E = in_sizes[1] / 2;      // 1600000
    const int* src = ei;
    const int* dst = ei + E;
    const int nbkt = (n + BW - 1) >> BSHIFT;   // 196

    const size_t n_pad = ((size_t)n + 256) & ~(size_t)255;  // room for row_start[n]

    // Workspace: bcnt(256) | bbase(512) | bcur(256) | row_start | dinv |
    //            ssrc | ebuf (E u32) | xh (n*32 u32, reused as t) |
    //            agg_x (n*32 u32) | w3f (2048 uint4) | w4f (1024 uint4)
    int*      bcnt      = (int*)d_ws;
    int*      bbase     = bcnt + 256;
    int*      bcur      = bbase + 512;
    int*      row_start = bcur + 256;
    float*    dinv      = (float*)(row_start + n_pad);
    int*      ssrc      = (int*)(dinv + n_pad);
    unsigned* ebuf      = (unsigned*)(ssrc + (((size_t)E + 255) & ~(size_t)255));
    unsigned* xh        = ebuf + (((size_t)E + 255) & ~(size_t)255);
    unsigned* agg_x     = xh + n_pad * 32;
    uint4*    w3f       = (uint4*)(agg_x + n_pad * 32);
    uint4*    w4f       = w3f + 2048;
    unsigned* t         = xh;                      // xh dead after agg1

    zero_small_kernel<<<1, 256, 0, stream>>>(bcnt, 256);
    wfrag_kernel<<<12, 256, 0, stream>>>(W3, W4, w3f, w4f);
    bhist_kernel<<<256, 256, 0, stream>>>(dst, bcnt, E, nbkt);
    bscan_kernel<<<1, 256, 0, stream>>>(bcnt, bbase, bcur, nbkt);

    bin_kernel<<<(E + TILE - 1) / TILE, 256, 0, stream>>>(src, dst, bcur, ebuf, E, nbkt);
    bucket_kernel<<<nbkt, 256, 0, stream>>>(ebuf, bbase, row_start, dinv, ssrc, n, E, nbkt);

    cvt_scaled_kernel<<<(n * 32 + 255) / 256, 256, 0, stream>>>(
        (const float2*)x, dinv, xh, n * 32);

    agg_f16_kernel<true, false><<<(n + 31) / 32, 256, 0, stream>>>(
        xh, row_start, ssrc, dinv, nullptr, agg_x, n);

    gemm12_kernel<<<(n + 127) / 128, 256, 0, stream>>>(
        agg_x, w3f, w4f, b3, dinv, t, n);

    agg_f16_kernel<false, true><<<(n + 31) / 32, 256, 0, stream>>>(
        t, row_start, ssrc, dinv, b4, out, n);
}